// Round 1
// 251.345 us; speedup vs baseline: 1.1805x; 1.1805x over previous
//
#include <hip/hip_runtime.h>
#include <hip/hip_bf16.h>

#define CHN 512
#define TLEN 2048
#define KSZ 5
#define BATCH 16

typedef __hip_bfloat16 bf16;
typedef short bf16x8 __attribute__((ext_vector_type(8)));   // 8 bf16 (4 VGPRs)
typedef float f32x4  __attribute__((ext_vector_type(4)));

// ws layout:
//   samp : float2[B*T*5]  (pos, sig)       = 1,310,720 B
//   w1t  : bf16 [16][3][256][40]           =   983,040 B   (pre-tiled W1)
//   wpk  : float[512][32]                  =    65,536 B   (packed ow+mw)
#define SAMP_BYTES (BATCH*TLEN*KSZ*8)
#define W1T_BYTES  (983040)
#define W1T_ELEMS  (16*3*256*40)

// ---------------------------------------------------------------------------
// kP: w1 fp32 [co][ci][r] -> w1t bf16 [ch][r][co][40] (32 data + 8 pad).
// ---------------------------------------------------------------------------
__global__ __launch_bounds__(256) void kP(const float* __restrict__ w1,
                                          bf16* __restrict__ w1t)
{
  int idx  = blockIdx.x*256 + threadIdx.x;       // < 491520, exact grid
  int c40  = idx % 40;
  int rest = idx / 40;
  int co   = rest & 255;
  int rr   = rest >> 8;          // ch*3 + r
  int r    = rr % 3;
  int ch   = rr / 3;
  float v = 0.f;
  if (c40 < 32) v = w1[(size_t)co*(CHN*3) + (ch*32 + c40)*3 + r];
  w1t[idx] = __float2bfloat16(v);
}

// ---------------------------------------------------------------------------
// kW: pack ow (5x512x3) and mw (5x512x3) -> wpk[c][32]:
//     j in [0,15)  : ow[o][c][d], j = o*3+d
//     j in [15,30) : mw[o][c][d], j = 15 + o*3+d
// 128B-aligned rows so kS can s_load_dwordx8 them.
// ---------------------------------------------------------------------------
__global__ __launch_bounds__(256) void kW(const float* __restrict__ ow,
    const float* __restrict__ mw, float* __restrict__ wpk)
{
  int idx = blockIdx.x*256 + threadIdx.x;        // < 16384, exact grid
  int j = idx & 31, c = idx >> 5;
  float v = 0.f;
  if (j < 15)      { int o = j/3,  d = j - o*3;  v = ow[o*(CHN*3) + c*3 + d]; }
  else if (j < 30) { int jj = j-15; int o = jj/3, d = jj - o*3;
                     v = mw[o*(CHN*3) + c*3 + d]; }
  wpk[idx] = v;
}

// ---------------------------------------------------------------------------
// kS: offset conv (out 0..4) + modulator conv (+sigmoid) -> sampling params.
// grid (TLEN/64, B), block (64 t, 8 cg). Each thread reduces 64 channels.
// Weight reads via readfirstlane-forced SMEM (s_load_dwordx8) -> VMEM pipe
// only carries the 3 x-loads per channel.
// samp[b,t,k] = (pos, sig); kDf re-derives base/wf/wc (bitwise-identical).
// ---------------------------------------------------------------------------
__global__ __launch_bounds__(512) void kS(const float* __restrict__ x,
    const float* __restrict__ wpk, const float* __restrict__ ob,
    const float* __restrict__ mb, float2* __restrict__ samp)
{
  int b  = blockIdx.y;
  int t0 = blockIdx.x*64;
  int tx = threadIdx.x;
  int cg = threadIdx.y;            // 0..7 (wave-uniform: wave = one tx row)
  int t  = t0 + tx;

  __shared__ float red[8][64][10];

  float acc[10];
  #pragma unroll
  for (int i=0;i<10;++i) acc[i]=0.f;
  const float* xb = x + (size_t)b*CHN*TLEN;
  int c0 = cg*64;
  #pragma unroll 4
  for (int c=c0;c<c0+64;++c) {
    int cu = __builtin_amdgcn_readfirstlane(c);
    const float* wp = wpk + cu*32;             // scalar -> s_load_dwordx8
    const float* xr = xb + (size_t)cu*TLEN;
    float xm = (t>0)      ? xr[t-1] : 0.f;
    float xc = xr[t];
    float xp = (t<TLEN-1) ? xr[t+1] : 0.f;
    #pragma unroll
    for (int o=0;o<5;++o) {
      acc[o]   = fmaf(xm, wp[o*3+0],    acc[o]);
      acc[o]   = fmaf(xc, wp[o*3+1],    acc[o]);
      acc[o]   = fmaf(xp, wp[o*3+2],    acc[o]);
      acc[5+o] = fmaf(xm, wp[15+o*3+0], acc[5+o]);
      acc[5+o] = fmaf(xc, wp[15+o*3+1], acc[5+o]);
      acc[5+o] = fmaf(xp, wp[15+o*3+2], acc[5+o]);
    }
  }
  #pragma unroll
  for (int i=0;i<10;++i) red[cg][tx][i] = acc[i];
  __syncthreads();
  for (int s=4;s>0;s>>=1) {
    if (cg < s) {
      #pragma unroll
      for (int i=0;i<10;++i) red[cg][tx][i] += red[cg+s][tx][i];
    }
    __syncthreads();
  }
  if (cg==0) {
    #pragma unroll
    for (int k=0;k<KSZ;++k) {
      float off = red[0][tx][k]   + ob[k];
      float mv  = red[0][tx][5+k] + mb[k];
      float sig = 1.f/(1.f + expf(-mv));
      float pos = (float)(t + k - 2) + off;
      pos = fminf(fmaxf(pos, 0.f), (float)(TLEN-1));
      samp[((size_t)b*TLEN + t)*KSZ + k] = make_float2(pos, sig);
    }
  }
}

// ---------------------------------------------------------------------------
// kDf: deformable sampling w/ diagonal weight — LDS-tiled.
// grid (T/128, C/64, B), block (64,4). Block stages x[c0..c0+63][lo..lo+159]
// into LDS via global_load_lds DMA (coalesced), then serves all gathers from
// LDS. Thread owns t = t0 + j*64 + tx (lane-consecutive) x 16 c-rows.
// Block-uniform fallback to global gathers if any base escapes the halo.
// ---------------------------------------------------------------------------
#define BT   128
#define HALO 16
#define XLEN 160   // BT + 2*HALO

__global__ __launch_bounds__(256) void kDf(const float* __restrict__ x,
    const float* __restrict__ wgt, const float2* __restrict__ sampg,
    float* __restrict__ out)
{
  int b  = blockIdx.z;
  int c0 = blockIdx.y*64;
  int t0 = blockIdx.x*BT;
  int tx = threadIdx.x, cy = threadIdx.y;
  int tid = cy*64 + tx;

  __shared__ float  xs[64*XLEN];    // 40,960 B
  __shared__ float2 sp[BT*KSZ];     //  5,120 B
  __shared__ int okf;

  int lo = min(max(t0 - HALO, 0), TLEN - XLEN);   // window always in-bounds

  if (tid == 0) okf = 1;
  for (int i = tid; i < BT*KSZ; i += 256)
    sp[i] = sampg[((size_t)b*TLEN + t0)*KSZ + i];

  // --- DMA x tile: 64 rows x 160 floats = 2560 float4 chunks, 10/thread.
  // LDS dest is linear (wave-uniform base + lane*16); src is per-lane.
  const float* xb = x + (size_t)b*CHN*TLEN;
  #pragma unroll
  for (int it = 0; it < 10; ++it) {
    int idx = tid + it*256;
    int c  = idx / 40;             // local c row
    int c4 = idx - c*40;           // float4 within row
    const float* src = xb + (size_t)(c0 + c)*TLEN + lo + c4*4;
    __builtin_amdgcn_global_load_lds(
        (const __attribute__((address_space(1))) unsigned int*)src,
        (__attribute__((address_space(3))) unsigned int*)&xs[idx*4],
        16, 0, 0);
  }
  __syncthreads();   // drains DMA (vmcnt) + sp writes (lgkm)

  // --- expand sampling params for this thread's 2x5 taps
  int   bl[2][KSZ];
  float wf[2][KSZ], wc[2][KSZ];
  bool ok = true;
  #pragma unroll
  for (int j=0;j<2;++j)
    #pragma unroll
    for (int k=0;k<KSZ;++k) {
      float2 s = sp[(j*64+tx)*KSZ + k];
      float pos = s.x, sig = s.y;
      float pf = floorf(pos), pc = ceilf(pos);
      int base = min((int)pf, TLEN-2);
      wf[j][k] = (pc - pos)*sig;     // ref quirk: pos integral -> wf=wc=0
      wc[j][k] = (pos - pf)*sig;
      int bloc = base - lo;
      bl[j][k] = bloc;
      ok = ok && (bloc >= 0) && (bloc <= XLEN-2);
    }
  if (!ok) okf = 0;
  __syncthreads();
  int fast = okf;    // block-uniform branch

  if (fast) {
    #pragma unroll 2
    for (int i=0;i<16;++i) {
      int cl = cy*16 + i;
      int cu = __builtin_amdgcn_readfirstlane(c0 + cl);
      const float* wd = wgt + (size_t)cu*(CHN*KSZ) + (size_t)cu*KSZ;  // diag
      float w0 = wd[0], w1v = wd[1], w2v = wd[2], w3 = wd[3], w4 = wd[4];
      const float* xr = xs + cl*XLEN;
      float o0, o1;
      {
        float a = 0.f;
        a = fmaf(fmaf(xr[bl[0][0]+1], wc[0][0], xr[bl[0][0]]*wf[0][0]), w0,  a);
        a = fmaf(fmaf(xr[bl[0][1]+1], wc[0][1], xr[bl[0][1]]*wf[0][1]), w1v, a);
        a = fmaf(fmaf(xr[bl[0][2]+1], wc[0][2], xr[bl[0][2]]*wf[0][2]), w2v, a);
        a = fmaf(fmaf(xr[bl[0][3]+1], wc[0][3], xr[bl[0][3]]*wf[0][3]), w3,  a);
        a = fmaf(fmaf(xr[bl[0][4]+1], wc[0][4], xr[bl[0][4]]*wf[0][4]), w4,  a);
        o0 = a;
      }
      {
        float a = 0.f;
        a = fmaf(fmaf(xr[bl[1][0]+1], wc[1][0], xr[bl[1][0]]*wf[1][0]), w0,  a);
        a = fmaf(fmaf(xr[bl[1][1]+1], wc[1][1], xr[bl[1][1]]*wf[1][1]), w1v, a);
        a = fmaf(fmaf(xr[bl[1][2]+1], wc[1][2], xr[bl[1][2]]*wf[1][2]), w2v, a);
        a = fmaf(fmaf(xr[bl[1][3]+1], wc[1][3], xr[bl[1][3]]*wf[1][3]), w3,  a);
        a = fmaf(fmaf(xr[bl[1][4]+1], wc[1][4], xr[bl[1][4]]*wf[1][4]), w4,  a);
        o1 = a;
      }
      size_t op = ((size_t)b*CHN + cu)*TLEN + t0 + tx;
      out[op]      = o0;
      out[op + 64] = o1;
    }
  } else {
    // slow path (never taken with bench weights): global gathers, same math
    for (int i=0;i<16;++i) {
      int cl = cy*16 + i;
      int cu = __builtin_amdgcn_readfirstlane(c0 + cl);
      const float* wd = wgt + (size_t)cu*(CHN*KSZ) + (size_t)cu*KSZ;
      float wk0 = wd[0], wk1 = wd[1], wk2 = wd[2], wk3 = wd[3], wk4 = wd[4];
      const float* xr = xb + (size_t)cu*TLEN + lo;   // xr[bl] == x[base]
      float o[2];
      #pragma unroll
      for (int j=0;j<2;++j) {
        float a = 0.f;
        a = fmaf(fmaf(xr[bl[j][0]+1], wc[j][0], xr[bl[j][0]]*wf[j][0]), wk0, a);
        a = fmaf(fmaf(xr[bl[j][1]+1], wc[j][1], xr[bl[j][1]]*wf[j][1]), wk1, a);
        a = fmaf(fmaf(xr[bl[j][2]+1], wc[j][2], xr[bl[j][2]]*wf[j][2]), wk2, a);
        a = fmaf(fmaf(xr[bl[j][3]+1], wc[j][3], xr[bl[j][3]]*wf[j][3]), wk3, a);
        a = fmaf(fmaf(xr[bl[j][4]+1], wc[j][4], xr[bl[j][4]]*wf[j][4]), wk4, a);
        o[j] = a;
      }
      size_t op = ((size_t)b*CHN + cu)*TLEN + t0 + tx;
      out[op]      = o[0];
      out[op + 64] = o[1];
    }
  }
}

// ---------------------------------------------------------------------------
// k2: fused rp1(conv3, 512->256)+ReLU+rp2(256->1)+bias, bf16 MFMA.
// H[co][n] = sum_ci sum_r W1[co][ci][r] * def[ci][t0+n+r-1]  (3 shifted GEMMs
// vs one def tile). Block: 512 thr, BM=256, BN=128, 16 iters of 32-ci chunks.
// ---------------------------------------------------------------------------
__global__ __launch_bounds__(512, 2) void k2(const float* __restrict__ def,
    const bf16* __restrict__ w1t, const float* __restrict__ b1,
    const float* __restrict__ w2, const float* __restrict__ b2p,
    float* __restrict__ outs)
{
  int n0 = blockIdx.x*128;
  int b  = n0 / TLEN;
  int t0 = n0 % TLEN;
  int tid  = threadIdx.x;
  int lane = tid & 63;
  int wave = tid >> 6;
  int wM   = wave & 3;             // 64-row co group
  int wN   = wave >> 2;            // 64-col n group
  int ln15 = lane & 15, quad = lane >> 4;

  __shared__ bf16 Ws[3*256*40];    // 61440 B
  __shared__ bf16 Dt[130*40];      // 10400 B
  __shared__ float Ss[128];

  f32x4 acc[4][4];
  #pragma unroll
  for (int i=0;i<4;++i)
    #pragma unroll
    for (int j=0;j<4;++j) acc[i][j] = (f32x4){0.f,0.f,0.f,0.f};

  for (int ch=0; ch<16; ++ch) {
    // --- async DMA: Ws <- w1t chunk (61440 B, 16B/lane, wave-uniform bases)
    const char* gsrc = (const char*)(w1t + (size_t)ch*(3*256*40));
    for (int of = tid*16; of < 61440; of += 8192) {
      __builtin_amdgcn_global_load_lds(
          (const __attribute__((address_space(1))) unsigned int*)(gsrc + of),
          (__attribute__((address_space(3))) unsigned int*)((char*)Ws + of),
          16, 0, 0);
    }
    // --- VGPR staging: Dt[tt][ci] <- def[ci0+ci][t0-1+tt], 32x130
    int ci0 = ch*32;
    #pragma unroll
    for (int j=0;j<9;++j) {
      int idx = tid + j*512;
      if (idx < 4160) {
        int ci = idx / 130, tt = idx - ci*130;
        int t = t0 - 1 + tt;
        float v = (t>=0 && t<TLEN)
            ? def[((size_t)b*CHN + ci0 + ci)*TLEN + t] : 0.f;
        Dt[tt*40 + ci] = __float2bfloat16(v);
      }
    }
    __syncthreads();   // drains DMA (vmcnt) + lds writes (lgkm)

    #pragma unroll
    for (int r=0;r<3;++r) {
      bf16x8 af[4], bfr[4];
      #pragma unroll
      for (int mt=0;mt<4;++mt)
        af[mt] = *(const bf16x8*)&Ws[(size_t)(r*256 + wM*64 + mt*16 + ln15)*40 + quad*8];
      #pragma unroll
      for (int nt=0;nt<4;++nt)
        bfr[nt] = *(const bf16x8*)&Dt[(size_t)(wN*64 + nt*16 + ln15 + r)*40 + quad*8];
      #pragma unroll
      for (int mt=0;mt<4;++mt)
        #pragma unroll
        for (int nt=0;nt<4;++nt)
          acc[mt][nt] = __builtin_amdgcn_mfma_f32_16x16x32_bf16(
              af[mt], bfr[nt], acc[mt][nt], 0, 0, 0);
    }
    __syncthreads();   // protect Ws/Dt before next chunk overwrites
  }

  // epilogue: strength[n] = sum_co relu(H[co][n]+b1[co]) * w2[co] + b2
  float part[4] = {0.f,0.f,0.f,0.f};
  #pragma unroll
  for (int mt=0;mt<4;++mt) {
    #pragma unroll
    for (int rr=0;rr<4;++rr) {
      int row = wM*64 + mt*16 + quad*4 + rr;
      float bias = b1[row];
      float wv   = w2[row];
      #pragma unroll
      for (int nt=0;nt<4;++nt) {
        float h = acc[mt][nt][rr] + bias;
        h = fmaxf(h, 0.f);
        part[nt] = fmaf(h, wv, part[nt]);
      }
    }
  }
  if (tid < 128) Ss[tid] = 0.f;
  __syncthreads();
  #pragma unroll
  for (int nt=0;nt<4;++nt)
    atomicAdd(&Ss[wN*64 + nt*16 + ln15], part[nt]);
  __syncthreads();
  if (tid < 128)
    outs[n0 + tid] = Ss[tid] + b2p[0];
}

extern "C" void kernel_launch(void* const* d_in, const int* in_sizes, int n_in,
                              void* d_out, int out_size, void* d_ws, size_t ws_size,
                              hipStream_t stream) {
  const float* x  = (const float*)d_in[0];
  const float* ow = (const float*)d_in[1];
  const float* ob = (const float*)d_in[2];
  const float* mw = (const float*)d_in[3];
  const float* mb = (const float*)d_in[4];
  const float* wg = (const float*)d_in[5];
  const float* w1 = (const float*)d_in[6];
  const float* b1 = (const float*)d_in[7];
  const float* w2 = (const float*)d_in[8];
  const float* b2 = (const float*)d_in[9];

  float* out_def = (float*)d_out;
  float* out_str = out_def + (size_t)BATCH*CHN*TLEN;

  float2* samp = (float2*)d_ws;                                  // 1.31 MB
  bf16*   w1t  = (bf16*)((char*)d_ws + SAMP_BYTES);              // 983 KB
  float*  wpk  = (float*)((char*)d_ws + SAMP_BYTES + W1T_BYTES); // 64 KB

  kP <<<dim3(W1T_ELEMS/256), 256, 0, stream>>>(w1, w1t);
  kW <<<dim3(64), 256, 0, stream>>>(ow, mw, wpk);
  kS <<<dim3(TLEN/64, BATCH), dim3(64,8), 0, stream>>>(x, wpk, ob, mb, samp);
  kDf<<<dim3(TLEN/BT, CHN/64, BATCH), dim3(64,4), 0, stream>>>(x, wg, samp, out_def);
  k2 <<<dim3(BATCH*TLEN/128), 512, 0, stream>>>(out_def, w1t, b1, w2, b2, out_str);
}

// Round 2
// 234.810 us; speedup vs baseline: 1.2637x; 1.0704x over previous
//
#include <hip/hip_runtime.h>
#include <hip/hip_bf16.h>

#define CHN 512
#define TLEN 2048
#define KSZ 5
#define BATCH 16

typedef __hip_bfloat16 bf16;
typedef short bf16x8 __attribute__((ext_vector_type(8)));   // 8 bf16 (4 VGPRs)
typedef float f32x4  __attribute__((ext_vector_type(4)));

// ws layout:
//   samp : float2[B*T*5]  (pos, sig)       = 1,310,720 B
//   w1t  : bf16 [16][3][256][40]           =   983,040 B   (pre-tiled W1)
//   wpk  : float[512][32]                  =    65,536 B   (packed ow+mw)
#define SAMP_BYTES (BATCH*TLEN*KSZ*8)
#define W1T_BYTES  (983040)
#define W1T_ELEMS  (16*3*256*40)

// ---------------------------------------------------------------------------
// kP: w1 fp32 [co][ci][r] -> w1t bf16 [ch][r][co][40] (32 data + 8 pad).
// ---------------------------------------------------------------------------
__global__ __launch_bounds__(256) void kP(const float* __restrict__ w1,
                                          bf16* __restrict__ w1t)
{
  int idx  = blockIdx.x*256 + threadIdx.x;       // < 491520, exact grid
  int c40  = idx % 40;
  int rest = idx / 40;
  int co   = rest & 255;
  int rr   = rest >> 8;          // ch*3 + r
  int r    = rr % 3;
  int ch   = rr / 3;
  float v = 0.f;
  if (c40 < 32) v = w1[(size_t)co*(CHN*3) + (ch*32 + c40)*3 + r];
  w1t[idx] = __float2bfloat16(v);
}

// ---------------------------------------------------------------------------
// kW: pack ow (5x512x3) and mw (5x512x3) -> wpk[c][32]:
//     j in [0,15)  : ow[o][c][d], j = o*3+d
//     j in [15,30) : mw[o][c][d], j = 15 + o*3+d
// 128B-aligned rows so kS can s_load_dwordx8 them.
// ---------------------------------------------------------------------------
__global__ __launch_bounds__(256) void kW(const float* __restrict__ ow,
    const float* __restrict__ mw, float* __restrict__ wpk)
{
  int idx = blockIdx.x*256 + threadIdx.x;        // < 16384, exact grid
  int j = idx & 31, c = idx >> 5;
  float v = 0.f;
  if (j < 15)      { int o = j/3,  d = j - o*3;  v = ow[o*(CHN*3) + c*3 + d]; }
  else if (j < 30) { int jj = j-15; int o = jj/3, d = jj - o*3;
                     v = mw[o*(CHN*3) + c*3 + d]; }
  wpk[idx] = v;
}

// ---------------------------------------------------------------------------
// kZ: outs[i] = b2  (k2 blocks atomically accumulate partial co-sums on top)
// ---------------------------------------------------------------------------
__global__ __launch_bounds__(256) void kZ(float* __restrict__ outs,
                                          const float* __restrict__ b2p)
{
  outs[blockIdx.x*256 + threadIdx.x] = b2p[0];
}

// ---------------------------------------------------------------------------
// kS: offset conv (out 0..4) + modulator conv (+sigmoid) -> sampling params.
// grid (TLEN/64, B), block (64 t, 8 cg). Each thread reduces 64 channels.
// samp[b,t,k] = (pos, sig); kDf re-derives base/wf/wc (bitwise-identical).
// ---------------------------------------------------------------------------
__global__ __launch_bounds__(512) void kS(const float* __restrict__ x,
    const float* __restrict__ wpk, const float* __restrict__ ob,
    const float* __restrict__ mb, float2* __restrict__ samp)
{
  int b  = blockIdx.y;
  int t0 = blockIdx.x*64;
  int tx = threadIdx.x;
  int cg = threadIdx.y;            // 0..7 (wave-uniform: wave = one tx row)
  int t  = t0 + tx;

  __shared__ float red[8][64][10];

  float acc[10];
  #pragma unroll
  for (int i=0;i<10;++i) acc[i]=0.f;
  const float* xb = x + (size_t)b*CHN*TLEN;
  int c0 = cg*64;
  #pragma unroll 4
  for (int c=c0;c<c0+64;++c) {
    int cu = __builtin_amdgcn_readfirstlane(c);
    const float* wp = wpk + cu*32;             // scalar -> s_load_dwordx8
    const float* xr = xb + (size_t)cu*TLEN;
    float xm = (t>0)      ? xr[t-1] : 0.f;
    float xc = xr[t];
    float xp = (t<TLEN-1) ? xr[t+1] : 0.f;
    #pragma unroll
    for (int o=0;o<5;++o) {
      acc[o]   = fmaf(xm, wp[o*3+0],    acc[o]);
      acc[o]   = fmaf(xc, wp[o*3+1],    acc[o]);
      acc[o]   = fmaf(xp, wp[o*3+2],    acc[o]);
      acc[5+o] = fmaf(xm, wp[15+o*3+0], acc[5+o]);
      acc[5+o] = fmaf(xc, wp[15+o*3+1], acc[5+o]);
      acc[5+o] = fmaf(xp, wp[15+o*3+2], acc[5+o]);
    }
  }
  #pragma unroll
  for (int i=0;i<10;++i) red[cg][tx][i] = acc[i];
  __syncthreads();
  for (int s=4;s>0;s>>=1) {
    if (cg < s) {
      #pragma unroll
      for (int i=0;i<10;++i) red[cg][tx][i] += red[cg+s][tx][i];
    }
    __syncthreads();
  }
  if (cg==0) {
    #pragma unroll
    for (int k=0;k<KSZ;++k) {
      float off = red[0][tx][k]   + ob[k];
      float mv  = red[0][tx][5+k] + mb[k];
      float sig = 1.f/(1.f + expf(-mv));
      float pos = (float)(t + k - 2) + off;
      pos = fminf(fmaxf(pos, 0.f), (float)(TLEN-1));
      samp[((size_t)b*TLEN + t)*KSZ + k] = make_float2(pos, sig);
    }
  }
}

// ---------------------------------------------------------------------------
// kDf: deformable sampling w/ diagonal weight — LDS-tiled.
// grid (T/128, C/64, B), block (64,4). Block stages x[c0..c0+63][lo..lo+159]
// into LDS via global_load_lds DMA (coalesced), then serves all gathers from
// LDS. Thread owns t = t0 + j*64 + tx (lane-consecutive) x 16 c-rows.
// Block-uniform fallback to global gathers if any base escapes the halo.
// ---------------------------------------------------------------------------
#define BT   128
#define HALO 16
#define XLEN 160   // BT + 2*HALO

__global__ __launch_bounds__(256) void kDf(const float* __restrict__ x,
    const float* __restrict__ wgt, const float2* __restrict__ sampg,
    float* __restrict__ out)
{
  int b  = blockIdx.z;
  int c0 = blockIdx.y*64;
  int t0 = blockIdx.x*BT;
  int tx = threadIdx.x, cy = threadIdx.y;
  int tid = cy*64 + tx;

  __shared__ float  xs[64*XLEN];    // 40,960 B
  __shared__ float2 sp[BT*KSZ];     //  5,120 B
  __shared__ int okf;

  int lo = min(max(t0 - HALO, 0), TLEN - XLEN);   // window always in-bounds

  if (tid == 0) okf = 1;
  for (int i = tid; i < BT*KSZ; i += 256)
    sp[i] = sampg[((size_t)b*TLEN + t0)*KSZ + i];

  // --- DMA x tile: 64 rows x 160 floats = 2560 float4 chunks, 10/thread.
  // LDS dest is linear (wave-uniform base + lane*16); src is per-lane.
  const float* xb = x + (size_t)b*CHN*TLEN;
  #pragma unroll
  for (int it = 0; it < 10; ++it) {
    int idx = tid + it*256;
    int c  = idx / 40;             // local c row
    int c4 = idx - c*40;           // float4 within row
    const float* src = xb + (size_t)(c0 + c)*TLEN + lo + c4*4;
    __builtin_amdgcn_global_load_lds(
        (const __attribute__((address_space(1))) unsigned int*)src,
        (__attribute__((address_space(3))) unsigned int*)&xs[idx*4],
        16, 0, 0);
  }
  __syncthreads();   // drains DMA (vmcnt) + sp writes (lgkm)

  // --- expand sampling params for this thread's 2x5 taps
  int   bl[2][KSZ];
  float wf[2][KSZ], wc[2][KSZ];
  bool ok = true;
  #pragma unroll
  for (int j=0;j<2;++j)
    #pragma unroll
    for (int k=0;k<KSZ;++k) {
      float2 s = sp[(j*64+tx)*KSZ + k];
      float pos = s.x, sig = s.y;
      float pf = floorf(pos), pc = ceilf(pos);
      int base = min((int)pf, TLEN-2);
      wf[j][k] = (pc - pos)*sig;     // ref quirk: pos integral -> wf=wc=0
      wc[j][k] = (pos - pf)*sig;
      int bloc = base - lo;
      bl[j][k] = bloc;
      ok = ok && (bloc >= 0) && (bloc <= XLEN-2);
    }
  if (!ok) okf = 0;
  __syncthreads();
  int fast = okf;    // block-uniform branch

  if (fast) {
    #pragma unroll 2
    for (int i=0;i<16;++i) {
      int cl = cy*16 + i;
      int cu = __builtin_amdgcn_readfirstlane(c0 + cl);
      const float* wd = wgt + (size_t)cu*(CHN*KSZ) + (size_t)cu*KSZ;  // diag
      float w0 = wd[0], w1v = wd[1], w2v = wd[2], w3 = wd[3], w4 = wd[4];
      const float* xr = xs + cl*XLEN;
      float o0, o1;
      {
        float a = 0.f;
        a = fmaf(fmaf(xr[bl[0][0]+1], wc[0][0], xr[bl[0][0]]*wf[0][0]), w0,  a);
        a = fmaf(fmaf(xr[bl[0][1]+1], wc[0][1], xr[bl[0][1]]*wf[0][1]), w1v, a);
        a = fmaf(fmaf(xr[bl[0][2]+1], wc[0][2], xr[bl[0][2]]*wf[0][2]), w2v, a);
        a = fmaf(fmaf(xr[bl[0][3]+1], wc[0][3], xr[bl[0][3]]*wf[0][3]), w3,  a);
        a = fmaf(fmaf(xr[bl[0][4]+1], wc[0][4], xr[bl[0][4]]*wf[0][4]), w4,  a);
        o0 = a;
      }
      {
        float a = 0.f;
        a = fmaf(fmaf(xr[bl[1][0]+1], wc[1][0], xr[bl[1][0]]*wf[1][0]), w0,  a);
        a = fmaf(fmaf(xr[bl[1][1]+1], wc[1][1], xr[bl[1][1]]*wf[1][1]), w1v, a);
        a = fmaf(fmaf(xr[bl[1][2]+1], wc[1][2], xr[bl[1][2]]*wf[1][2]), w2v, a);
        a = fmaf(fmaf(xr[bl[1][3]+1], wc[1][3], xr[bl[1][3]]*wf[1][3]), w3,  a);
        a = fmaf(fmaf(xr[bl[1][4]+1], wc[1][4], xr[bl[1][4]]*wf[1][4]), w4,  a);
        o1 = a;
      }
      size_t op = ((size_t)b*CHN + cu)*TLEN + t0 + tx;
      out[op]      = o0;
      out[op + 64] = o1;
    }
  } else {
    // slow path (never taken with bench weights): global gathers, same math
    for (int i=0;i<16;++i) {
      int cl = cy*16 + i;
      int cu = __builtin_amdgcn_readfirstlane(c0 + cl);
      const float* wd = wgt + (size_t)cu*(CHN*KSZ) + (size_t)cu*KSZ;
      float wk0 = wd[0], wk1 = wd[1], wk2 = wd[2], wk3 = wd[3], wk4 = wd[4];
      const float* xr = xb + (size_t)cu*TLEN + lo;   // xr[bl] == x[base]
      float o[2];
      #pragma unroll
      for (int j=0;j<2;++j) {
        float a = 0.f;
        a = fmaf(fmaf(xr[bl[j][0]+1], wc[j][0], xr[bl[j][0]]*wf[j][0]), wk0, a);
        a = fmaf(fmaf(xr[bl[j][1]+1], wc[j][1], xr[bl[j][1]]*wf[j][1]), wk1, a);
        a = fmaf(fmaf(xr[bl[j][2]+1], wc[j][2], xr[bl[j][2]]*wf[j][2]), wk2, a);
        a = fmaf(fmaf(xr[bl[j][3]+1], wc[j][3], xr[bl[j][3]]*wf[j][3]), wk3, a);
        a = fmaf(fmaf(xr[bl[j][4]+1], wc[j][4], xr[bl[j][4]]*wf[j][4]), wk4, a);
        o[j] = a;
      }
      size_t op = ((size_t)b*CHN + cu)*TLEN + t0 + tx;
      out[op]      = o[0];
      out[op + 64] = o[1];
    }
  }
}

// ---------------------------------------------------------------------------
// k2: fused rp1(conv3, 512->256)+ReLU+rp2(256->1)+bias, bf16 MFMA.
// H[co][n] = sum_ci sum_r W1[co][ci][r] * def[ci][t0+n+r-1]  (3 shifted GEMMs
// vs one def tile). Grid (256 n-tiles, 2 co-halves), 256 thr (4 waves),
// BM=128, BN=128; 2 blocks/CU overlap each other's staging + MFMA phases.
// Dt staged as bf16x8 per thread -> conflict-free ds_write_b128 (80B lane
// stride tiles all 32 banks per 8-lane group). Partial co-sums accumulate
// into outs (pre-set to b2 by kZ) via one global atomicAdd per (block,n).
// ---------------------------------------------------------------------------
__global__ __launch_bounds__(256, 2) void k2(const float* __restrict__ def,
    const bf16* __restrict__ w1t, const float* __restrict__ b1,
    const float* __restrict__ w2, float* __restrict__ outs)
{
  int n0 = blockIdx.x*128;
  int m0 = blockIdx.y;             // 0,1: co half
  int b  = n0 / TLEN;
  int t0 = n0 % TLEN;
  int tid  = threadIdx.x;          // 0..255
  int lane = tid & 63;
  int wave = tid >> 6;             // 0..3
  int wM   = wave & 1;             // 64-row co group
  int wN   = wave >> 1;            // 64-col n group
  int ln15 = lane & 15, quad = lane >> 4;

  __shared__ bf16 Ws[3*128*40];    // 30720 B
  __shared__ bf16 Dt[130*40];      // 10400 B
  __shared__ float Ss[128];

  f32x4 acc[4][4];
  #pragma unroll
  for (int i=0;i<4;++i)
    #pragma unroll
    for (int j=0;j<4;++j) acc[i][j] = (f32x4){0.f,0.f,0.f,0.f};

  for (int ch=0; ch<16; ++ch) {
    // --- async DMA: Ws <- w1t chunk, 3 spans of 10240 B (co half m0)
    #pragma unroll
    for (int r=0;r<3;++r) {
      const char* gs = (const char*)(w1t + ((size_t)(ch*3+r)*256 + m0*128)*40);
      char* ld = (char*)Ws + r*10240;
      for (int of = tid*16; of < 10240; of += 4096) {
        __builtin_amdgcn_global_load_lds(
            (const __attribute__((address_space(1))) unsigned int*)(gs + of),
            (__attribute__((address_space(3))) unsigned int*)(ld + of),
            16, 0, 0);
      }
    }
    // --- Dt[tt][ci] <- def[ci0+ci][t0-1+tt]: thread packs 8 ci for one tt,
    // single ds_write_b128 (conflict-free). 520 slots = 130 tt x 4 ci-octets.
    int ci0 = ch*32;
    for (int s = tid; s < 520; s += 256) {
      int g  = s / 130;            // ci octet 0..3
      int tt = s - g*130;
      int t  = t0 - 1 + tt;
      bf16x8 v = (bf16x8){0,0,0,0,0,0,0,0};
      if (t >= 0 && t < TLEN) {
        const float* dp = def + ((size_t)b*CHN + ci0 + g*8)*TLEN + t;
        #pragma unroll
        for (int j=0;j<8;++j) {
          union { bf16 h; short u; } cv;
          cv.h = __float2bfloat16(dp[(size_t)j*TLEN]);
          v[j] = cv.u;
        }
      }
      *(bf16x8*)((char*)Dt + tt*80 + g*16) = v;
    }
    __syncthreads();   // drains DMA (vmcnt) + lds writes (lgkm)

    #pragma unroll
    for (int r=0;r<3;++r) {
      bf16x8 af[4], bfr[4];
      #pragma unroll
      for (int mt=0;mt<4;++mt)
        af[mt] = *(const bf16x8*)&Ws[(size_t)(r*128 + wM*64 + mt*16 + ln15)*40 + quad*8];
      #pragma unroll
      for (int nt=0;nt<4;++nt)
        bfr[nt] = *(const bf16x8*)&Dt[(size_t)(wN*64 + nt*16 + ln15 + r)*40 + quad*8];
      #pragma unroll
      for (int mt=0;mt<4;++mt)
        #pragma unroll
        for (int nt=0;nt<4;++nt)
          acc[mt][nt] = __builtin_amdgcn_mfma_f32_16x16x32_bf16(
              af[mt], bfr[nt], acc[mt][nt], 0, 0, 0);
    }
    __syncthreads();   // protect Ws/Dt before next chunk overwrites
  }

  // epilogue: strength[n] += sum_{co in half} relu(H[co][n]+b1[co]) * w2[co]
  float part[4] = {0.f,0.f,0.f,0.f};
  #pragma unroll
  for (int mt=0;mt<4;++mt) {
    #pragma unroll
    for (int rr=0;rr<4;++rr) {
      int row = m0*128 + wM*64 + mt*16 + quad*4 + rr;
      float bias = b1[row];
      float wv   = w2[row];
      #pragma unroll
      for (int nt=0;nt<4;++nt) {
        float h = acc[mt][nt][rr] + bias;
        h = fmaxf(h, 0.f);
        part[nt] = fmaf(h, wv, part[nt]);
      }
    }
  }
  if (tid < 128) Ss[tid] = 0.f;
  __syncthreads();
  #pragma unroll
  for (int nt=0;nt<4;++nt)
    atomicAdd(&Ss[wN*64 + nt*16 + ln15], part[nt]);
  __syncthreads();
  if (tid < 128)
    atomicAdd(&outs[n0 + tid], Ss[tid]);
}

extern "C" void kernel_launch(void* const* d_in, const int* in_sizes, int n_in,
                              void* d_out, int out_size, void* d_ws, size_t ws_size,
                              hipStream_t stream) {
  const float* x  = (const float*)d_in[0];
  const float* ow = (const float*)d_in[1];
  const float* ob = (const float*)d_in[2];
  const float* mw = (const float*)d_in[3];
  const float* mb = (const float*)d_in[4];
  const float* wg = (const float*)d_in[5];
  const float* w1 = (const float*)d_in[6];
  const float* b1 = (const float*)d_in[7];
  const float* w2 = (const float*)d_in[8];
  const float* b2 = (const float*)d_in[9];

  float* out_def = (float*)d_out;
  float* out_str = out_def + (size_t)BATCH*CHN*TLEN;

  float2* samp = (float2*)d_ws;                                  // 1.31 MB
  bf16*   w1t  = (bf16*)((char*)d_ws + SAMP_BYTES);              // 983 KB
  float*  wpk  = (float*)((char*)d_ws + SAMP_BYTES + W1T_BYTES); // 64 KB

  kP <<<dim3(W1T_ELEMS/256), 256, 0, stream>>>(w1, w1t);
  kW <<<dim3(64), 256, 0, stream>>>(ow, mw, wpk);
  kZ <<<dim3(BATCH*TLEN/256), 256, 0, stream>>>(out_str, b2);
  kS <<<dim3(TLEN/64, BATCH), dim3(64,8), 0, stream>>>(x, wpk, ob, mb, samp);
  kDf<<<dim3(TLEN/BT, CHN/64, BATCH), dim3(64,4), 0, stream>>>(x, wg, samp, out_def);
  k2 <<<dim3(BATCH*TLEN/128, 2), 256, 0, stream>>>(out_def, w1t, b1, w2, out_str);
}